// Round 12
// baseline (319.083 us; speedup 1.0000x reference)
//
#include <hip/hip_runtime.h>
#include <hip/hip_bf16.h>
#include <hip/hip_fp16.h>

constexpr int HDIM = 8;
constexpr int EDIM = 8;

__device__ __forceinline__ unsigned pack2h(float a, float b) {
  __half2 h = __floats2half2_rn(a, b);
  union { __half2 h2; unsigned u; } u;
  u.h2 = h;
  return u.u;
}

__device__ __forceinline__ __half2 u2h2(unsigned v) {
  union { unsigned u; __half2 h2; } u;
  u.u = v;
  return u.h2;
}

// h = x @ node_W + node_b, fused with layer-0 BN stats (8-slot) and deg zeroing.
__global__ __launch_bounds__(256) void init_h_stats_kernel(
    const float* __restrict__ x, const float* __restrict__ W, const float* __restrict__ b,
    float* __restrict__ h, float* __restrict__ sums, int* __restrict__ deg, int n) {
  __shared__ float reds[256], redq[256];
  int tid = threadIdx.x, lane = tid & 63;
  int gtid = blockIdx.x * 256 + tid;
  for (int i = gtid; i < n; i += 512 * 256) deg[i] = 0;
  float wc[HDIM];
#pragma unroll
  for (int k = 0; k < HDIM; ++k) wc[k] = W[k * 64 + lane];
  float bc = b[lane];
  float s = 0.f, q = 0.f;
  int total = n * 64;
  for (int gid = gtid; gid < total; gid += 512 * 256) {
    int row = gid >> 6;
    const float* xr = x + (size_t)row * HDIM;
    float acc = bc;
#pragma unroll
    for (int k = 0; k < HDIM; ++k) acc = fmaf(xr[k], wc[k], acc);
    h[gid] = acc;
    s += acc;
    q = fmaf(acc, acc, q);
  }
  reds[tid] = s; redq[tid] = q;
  __syncthreads();
  if (tid < 64) {
    float S = reds[tid] + reds[64 + tid] + reds[128 + tid] + reds[192 + tid];
    float Q = redq[tid] + redq[64 + tid] + redq[128 + tid] + redq[192 + tid];
    int slot = blockIdx.x & 7;
    atomicAdd(&sums[slot * 128 + tid], S);
    atomicAdd(&sums[slot * 128 + 64 + tid], Q);
  }
}

// degree histogram + per-edge within-dst index
__global__ void deg_kernel(const int* __restrict__ dst, int* __restrict__ deg,
                           int* __restrict__ idxw, int E) {
  int e = blockIdx.x * 256 + threadIdx.x;
  if (e < E) idxw[e] = atomicAdd(&deg[dst[e]], 1);
}

// 3-dispatch device-wide exclusive scan
__global__ __launch_bounds__(256) void scan_part_kernel(const int* __restrict__ deg,
                                                        int* __restrict__ partials, int n) {
  __shared__ int sh[256];
  int tid = threadIdx.x, idx = blockIdx.x * 256 + tid;
  int v = (idx < n) ? deg[idx] : 0;
  sh[tid] = v;
  __syncthreads();
  for (int o = 128; o > 0; o >>= 1) {
    if (tid < o) sh[tid] += sh[tid + o];
    __syncthreads();
  }
  if (tid == 0) partials[blockIdx.x] = sh[0];
}

__global__ __launch_bounds__(1024) void scan_top_kernel(int* __restrict__ partials, int nb) {
  __shared__ int sh[1024];
  int tid = threadIdx.x;
  int v = (tid < nb) ? partials[tid] : 0;
  sh[tid] = v;
  __syncthreads();
  for (int o = 1; o < 1024; o <<= 1) {
    int a = (tid >= o) ? sh[tid - o] : 0;
    __syncthreads();
    sh[tid] += a;
    __syncthreads();
  }
  if (tid < nb) partials[tid] = sh[tid] - v;  // exclusive
}

__global__ __launch_bounds__(256) void scan_fill_kernel(
    const int* __restrict__ deg, const int* __restrict__ partials,
    int* __restrict__ rowstart, int n, int total) {
  __shared__ int sh[256];
  int tid = threadIdx.x, idx = blockIdx.x * 256 + tid;
  int v = (idx < n) ? deg[idx] : 0;
  sh[tid] = v;
  __syncthreads();
  for (int o = 1; o < 256; o <<= 1) {
    int a = (tid >= o) ? sh[tid - o] : 0;
    __syncthreads();
    sh[tid] += a;
    __syncthreads();
  }
  if (idx < n) rowstart[idx] = partials[blockIdx.x] + sh[tid] - v;
  if (blockIdx.x == 0 && tid == 0) rowstart[n] = total;
}

// scatter ONE 32B record per edge: {f16 ea[8] (16B), src (4B), pad}. No atomics.
__global__ void fill_kernel(const int* __restrict__ src, const int* __restrict__ dst,
                            const int* __restrict__ idxw, const int* __restrict__ rowstart,
                            const float* __restrict__ edge_attr, char* __restrict__ recs, int E) {
  int e = blockIdx.x * 256 + threadIdx.x;
  if (e >= E) return;
  int d = dst[e];
  int slot = rowstart[d] + idxw[e];
  const float4* ap = (const float4*)(edge_attr + (size_t)e * EDIM);
  float4 a = ap[0], c = ap[1];
  uint4 rv;
  rv.x = pack2h(a.x, a.y);
  rv.y = pack2h(a.z, a.w);
  rv.z = pack2h(c.x, c.y);
  rv.w = pack2h(c.z, c.w);
  char* rb = recs + (size_t)slot * 32;
  *(uint4*)rb = rv;
  *(int*)(rb + 16) = src[e];
}

// Per-layer BN+ReLU applied once per node -> f16 hn buffer (6.4MB; halves gather bytes)
__global__ __launch_bounds__(256) void bn_apply_kernel(
    const float* __restrict__ h, const float* __restrict__ sums,
    const float* __restrict__ bn_g, const float* __restrict__ bn_b,
    unsigned short* __restrict__ hn, int n, float invN) {
  int tid0 = blockIdx.x * 256 + threadIdx.x;
  int lane = tid0 & 63;
  float ssum = 0.f, qsum = 0.f;
#pragma unroll
  for (int k = 0; k < 8; ++k) {
    ssum += sums[k * 128 + lane];
    qsum += sums[k * 128 + 64 + lane];
  }
  float mu = ssum * invN;
  float var = qsum * invN - mu * mu;
  float a = rsqrtf(var + 1e-5f) * bn_g[lane];
  float c = bn_b[lane] - mu * a;
  int total = n * 64;
  for (int gid = tid0; gid < total; gid += 512 * 256) {  // stride % 64 == 0: lane fixed
    float v = fmaxf(fmaf(h[gid], a, c), 0.f);
    hn[gid] = __half_as_ushort(__float2half(v));
  }
}

// Fused message + softmax-agg on precomputed f16 hn. 1 wave/node, lane=channel.
// Edge dot via packed hfma2 (4 ops); x8 unrolled gather pipeline.
__global__ __launch_bounds__(256) void aggregate_kernel(
    const unsigned short* __restrict__ hn, const int* __restrict__ rowstart,
    const char* __restrict__ recs, const float* __restrict__ edge_W,
    const float* __restrict__ edge_b, const float* __restrict__ t,
    float* __restrict__ out, int n) {
  int lane = threadIdx.x & 63;
  int node = blockIdx.x * 4 + (threadIdx.x >> 6);
  if (node >= n) return;
  __half2 wc2[4];
#pragma unroll
  for (int k = 0; k < 4; ++k)
    wc2[k] = __floats2half2_rn(edge_W[(2 * k) * 64 + lane], edge_W[(2 * k + 1) * 64 + lane]);
  float eb = edge_b[lane];
  float tt = t[0];
  int s0 = __builtin_amdgcn_readfirstlane(rowstart[node]);
  int s1 = __builtin_amdgcn_readfirstlane(rowstart[node + 1]);
  float hd = __half2float(__ushort_as_half(hn[(size_t)node * 64 + lane]));
  float den = 0.f, num = 0.f;
#define EDGE_STEP(HU, RV)                                                      \
  {                                                                            \
    __half2 acc = __hmul2(u2h2(RV.w), wc2[3]);                                 \
    acc = __hfma2(u2h2(RV.z), wc2[2], acc);                                    \
    acc = __hfma2(u2h2(RV.y), wc2[1], acc);                                    \
    acc = __hfma2(u2h2(RV.x), wc2[0], acc);                                    \
    float ev = __low2float(acc) + __high2float(acc) + eb;                      \
    float hnv = __half2float(__ushort_as_half(HU));                            \
    float msg = fmaxf(hnv + ev, 0.f) + 1e-7f;                                  \
    float p = __expf(msg * tt);                                                \
    den += p;                                                                  \
    num = fmaf(p, msg, num);                                                   \
  }
  int j = s0;
  for (; j + 8 <= s1; j += 8) {
    const char* rb = recs + (size_t)j * 32;
    uint4 r0 = *(const uint4*)(rb);
    uint4 r1 = *(const uint4*)(rb + 32);
    uint4 r2 = *(const uint4*)(rb + 64);
    uint4 r3 = *(const uint4*)(rb + 96);
    uint4 r4 = *(const uint4*)(rb + 128);
    uint4 r5 = *(const uint4*)(rb + 160);
    uint4 r6 = *(const uint4*)(rb + 192);
    uint4 r7 = *(const uint4*)(rb + 224);
    int i0 = *(const int*)(rb + 16);
    int i1 = *(const int*)(rb + 48);
    int i2 = *(const int*)(rb + 80);
    int i3 = *(const int*)(rb + 112);
    int i4 = *(const int*)(rb + 144);
    int i5 = *(const int*)(rb + 176);
    int i6 = *(const int*)(rb + 208);
    int i7 = *(const int*)(rb + 240);
    unsigned short u0 = hn[(size_t)i0 * 64 + lane];
    unsigned short u1 = hn[(size_t)i1 * 64 + lane];
    unsigned short u2 = hn[(size_t)i2 * 64 + lane];
    unsigned short u3 = hn[(size_t)i3 * 64 + lane];
    unsigned short u4 = hn[(size_t)i4 * 64 + lane];
    unsigned short u5 = hn[(size_t)i5 * 64 + lane];
    unsigned short u6 = hn[(size_t)i6 * 64 + lane];
    unsigned short u7 = hn[(size_t)i7 * 64 + lane];
    EDGE_STEP(u0, r0)
    EDGE_STEP(u1, r1)
    EDGE_STEP(u2, r2)
    EDGE_STEP(u3, r3)
    EDGE_STEP(u4, r4)
    EDGE_STEP(u5, r5)
    EDGE_STEP(u6, r6)
    EDGE_STEP(u7, r7)
  }
  for (; j + 4 <= s1; j += 4) {
    const char* rb = recs + (size_t)j * 32;
    uint4 r0 = *(const uint4*)(rb);
    uint4 r1 = *(const uint4*)(rb + 32);
    uint4 r2 = *(const uint4*)(rb + 64);
    uint4 r3 = *(const uint4*)(rb + 96);
    int i0 = *(const int*)(rb + 16);
    int i1 = *(const int*)(rb + 48);
    int i2 = *(const int*)(rb + 80);
    int i3 = *(const int*)(rb + 112);
    unsigned short u0 = hn[(size_t)i0 * 64 + lane];
    unsigned short u1 = hn[(size_t)i1 * 64 + lane];
    unsigned short u2 = hn[(size_t)i2 * 64 + lane];
    unsigned short u3 = hn[(size_t)i3 * 64 + lane];
    EDGE_STEP(u0, r0)
    EDGE_STEP(u1, r1)
    EDGE_STEP(u2, r2)
    EDGE_STEP(u3, r3)
  }
  for (; j < s1; ++j) {
    const char* rb = recs + (size_t)j * 32;
    uint4 r0 = *(const uint4*)(rb);
    int i0 = *(const int*)(rb + 16);
    unsigned short u0 = hn[(size_t)i0 * 64 + lane];
    EDGE_STEP(u0, r0)
  }
#undef EDGE_STEP
  out[(size_t)node * 64 + lane] = num / fmaxf(den, 1e-16f) + hd;
}

// Tiled-GEMM MLP: 256 threads, 64 nodes/block. Two-pass phase2 reuses the 64-row
// bufA for zT halves -> LDS 50.7KB -> 3 blocks/CU.
__global__ __launch_bounds__(256) void mlp_tile_kernel(
    const float* __restrict__ outv, const float* __restrict__ h_in,
    const float* __restrict__ W1, const float* __restrict__ b1,
    const float* __restrict__ lng, const float* __restrict__ lnb,
    const float* __restrict__ W2, const float* __restrict__ b2,
    float* __restrict__ h_out, float* __restrict__ nextsums, int n) {
  __shared__ float bufA[64 * 68];   // xT -> LN partials -> zT half -> out partials
  __shared__ float bufB[64 * 128];  // W1s then W2s
  __shared__ float mstat[128];      // mu[64], rstd[64]
  const int tid = threadIdx.x;
  const int tx = tid & 15, ty = tid >> 4;
  const int n0 = blockIdx.x * 64;
#pragma unroll
  for (int i = 0; i < 16; ++i) {
    int gid = i * 256 + tid;
    int node = gid >> 6, c = gid & 63;
    int nd = n0 + node;
    bufA[c * 68 + node] = (nd < n) ? outv[(size_t)nd * 64 + c] : 0.f;
  }
  {
    const float4* w1g = (const float4*)W1;
    float4* w1s = (float4*)bufB;
#pragma unroll
    for (int i = 0; i < 8; ++i) w1s[i * 256 + tid] = w1g[i * 256 + tid];
  }
  __syncthreads();
  const float4* b1v = (const float4*)b1;
  float4 acc0[4], acc1[4];
  {
    float4 bA = b1v[2 * ty], bB = b1v[2 * ty + 1];
#pragma unroll
    for (int i = 0; i < 4; ++i) { acc0[i] = bA; acc1[i] = bB; }
  }
  for (int k = 0; k < 64; ++k) {
    float4 xv = *(const float4*)&bufA[k * 68 + 4 * tx];
    float4 w0 = *(const float4*)&bufB[k * 128 + 8 * ty];
    float4 w1 = *(const float4*)&bufB[k * 128 + 8 * ty + 4];
#define FMA8(I, XS)                                                            \
    acc0[I].x = fmaf(XS, w0.x, acc0[I].x);                                     \
    acc0[I].y = fmaf(XS, w0.y, acc0[I].y);                                     \
    acc0[I].z = fmaf(XS, w0.z, acc0[I].z);                                     \
    acc0[I].w = fmaf(XS, w0.w, acc0[I].w);                                     \
    acc1[I].x = fmaf(XS, w1.x, acc1[I].x);                                     \
    acc1[I].y = fmaf(XS, w1.y, acc1[I].y);                                     \
    acc1[I].z = fmaf(XS, w1.z, acc1[I].z);                                     \
    acc1[I].w = fmaf(XS, w1.w, acc1[I].w);
    FMA8(0, xv.x) FMA8(1, xv.y) FMA8(2, xv.z) FMA8(3, xv.w)
#undef FMA8
  }
  __syncthreads();
  float* redS = bufA;
  float* redQ = bufA + 16 * 68;
#pragma unroll
  for (int i = 0; i < 4; ++i) {
    float si = ((acc0[i].x + acc0[i].y) + (acc0[i].z + acc0[i].w)) +
               ((acc1[i].x + acc1[i].y) + (acc1[i].z + acc1[i].w));
    float qi = 0.f;
    qi = fmaf(acc0[i].x, acc0[i].x, qi); qi = fmaf(acc0[i].y, acc0[i].y, qi);
    qi = fmaf(acc0[i].z, acc0[i].z, qi); qi = fmaf(acc0[i].w, acc0[i].w, qi);
    qi = fmaf(acc1[i].x, acc1[i].x, qi); qi = fmaf(acc1[i].y, acc1[i].y, qi);
    qi = fmaf(acc1[i].z, acc1[i].z, qi); qi = fmaf(acc1[i].w, acc1[i].w, qi);
    redS[ty * 68 + 4 * tx + i] = si;
    redQ[ty * 68 + 4 * tx + i] = qi;
  }
  {
    const float4* w2g = (const float4*)W2;
    float4* w2s = (float4*)bufB;
#pragma unroll
    for (int i = 0; i < 8; ++i) w2s[i * 256 + tid] = w2g[i * 256 + tid];
  }
  __syncthreads();
  if (tid < 64) {
    float S = 0.f, Q = 0.f;
#pragma unroll
    for (int t = 0; t < 16; ++t) { S += redS[t * 68 + tid]; Q += redQ[t * 68 + tid]; }
    float mu = S * (1.f / 128.f);
    float var = Q * (1.f / 128.f) - mu * mu;
    mstat[tid] = mu;
    mstat[64 + tid] = rsqrtf(var + 1e-5f);
  }
  __syncthreads();
  float mu0 = mstat[4 * tx + 0], mu1 = mstat[4 * tx + 1];
  float mu2 = mstat[4 * tx + 2], mu3 = mstat[4 * tx + 3];
  float r0 = mstat[64 + 4 * tx + 0], r1 = mstat[64 + 4 * tx + 1];
  float r2 = mstat[64 + 4 * tx + 2], r3 = mstat[64 + 4 * tx + 3];
  const float4* lgv = (const float4*)lng;
  const float4* lbv = (const float4*)lnb;
  float4 g0 = lgv[2 * ty], g1 = lgv[2 * ty + 1];
  float4 e0 = lbv[2 * ty], e1 = lbv[2 * ty + 1];
#define ZROW(ROWLOCAL, A, C, G, E)                                             \
  { float4 zr;                                                                 \
    zr.x = fmaxf((A[0].C - mu0) * r0 * (G).C + (E).C, 0.f);                    \
    zr.y = fmaxf((A[1].C - mu1) * r1 * (G).C + (E).C, 0.f);                    \
    zr.z = fmaxf((A[2].C - mu2) * r2 * (G).C + (E).C, 0.f);                    \
    zr.w = fmaxf((A[3].C - mu3) * r3 * (G).C + (E).C, 0.f);                    \
    *(float4*)&bufA[(ROWLOCAL) * 68 + 4 * tx] = zr; }
  if (ty < 8) {
    ZROW(8 * ty + 0, acc0, x, g0, e0)
    ZROW(8 * ty + 1, acc0, y, g0, e0)
    ZROW(8 * ty + 2, acc0, z, g0, e0)
    ZROW(8 * ty + 3, acc0, w, g0, e0)
    ZROW(8 * ty + 4, acc1, x, g1, e1)
    ZROW(8 * ty + 5, acc1, y, g1, e1)
    ZROW(8 * ty + 6, acc1, z, g1, e1)
    ZROW(8 * ty + 7, acc1, w, g1, e1)
  }
  __syncthreads();
  float4 oa[4];
  {
    float4 bc = ((const float4*)b2)[ty];
#pragma unroll
    for (int i = 0; i < 4; ++i) oa[i] = bc;
  }
#define P2(I, ZS, WV)                                                          \
  oa[I].x = fmaf(ZS, WV.x, oa[I].x);                                           \
  oa[I].y = fmaf(ZS, WV.y, oa[I].y);                                           \
  oa[I].z = fmaf(ZS, WV.z, oa[I].z);                                           \
  oa[I].w = fmaf(ZS, WV.w, oa[I].w);
  for (int k = 0; k < 64; ++k) {
    float4 zv = *(const float4*)&bufA[k * 68 + 4 * tx];
    float4 wv = *(const float4*)&bufB[k * 64 + 4 * ty];
    P2(0, zv.x, wv) P2(1, zv.y, wv) P2(2, zv.z, wv) P2(3, zv.w, wv)
  }
  __syncthreads();
  if (ty >= 8) {
    int tyb = ty - 8;
    ZROW(8 * tyb + 0, acc0, x, g0, e0)
    ZROW(8 * tyb + 1, acc0, y, g0, e0)
    ZROW(8 * tyb + 2, acc0, z, g0, e0)
    ZROW(8 * tyb + 3, acc0, w, g0, e0)
    ZROW(8 * tyb + 4, acc1, x, g1, e1)
    ZROW(8 * tyb + 5, acc1, y, g1, e1)
    ZROW(8 * tyb + 6, acc1, z, g1, e1)
    ZROW(8 * tyb + 7, acc1, w, g1, e1)
  }
  __syncthreads();
  for (int k = 64; k < 128; ++k) {
    float4 zv = *(const float4*)&bufA[(k - 64) * 68 + 4 * tx];
    float4 wv = *(const float4*)&bufB[k * 64 + 4 * ty];
    P2(0, zv.x, wv) P2(1, zv.y, wv) P2(2, zv.z, wv) P2(3, zv.w, wv)
  }
#undef P2
#undef ZROW
  float4 ps = make_float4(0.f, 0.f, 0.f, 0.f);
  float4 pq = make_float4(0.f, 0.f, 0.f, 0.f);
#pragma unroll
  for (int i = 0; i < 4; ++i) {
    int nd = n0 + 4 * tx + i;
    if (nd < n) {
      float4 hv = *(const float4*)&h_in[(size_t)nd * 64 + 4 * ty];
      float4 v;
      v.x = hv.x + oa[i].x; v.y = hv.y + oa[i].y;
      v.z = hv.z + oa[i].z; v.w = hv.w + oa[i].w;
      *(float4*)&h_out[(size_t)nd * 64 + 4 * ty] = v;
      ps.x += v.x; ps.y += v.y; ps.z += v.z; ps.w += v.w;
      pq.x = fmaf(v.x, v.x, pq.x); pq.y = fmaf(v.y, v.y, pq.y);
      pq.z = fmaf(v.z, v.z, pq.z); pq.w = fmaf(v.w, v.w, pq.w);
    }
  }
  if (nextsums != nullptr) {
    __syncthreads();
    float* rs = bufA;
    float* rq = bufA + 64 * 17;
    rs[(4 * ty + 0) * 17 + tx] = ps.x;
    rs[(4 * ty + 1) * 17 + tx] = ps.y;
    rs[(4 * ty + 2) * 17 + tx] = ps.z;
    rs[(4 * ty + 3) * 17 + tx] = ps.w;
    rq[(4 * ty + 0) * 17 + tx] = pq.x;
    rq[(4 * ty + 1) * 17 + tx] = pq.y;
    rq[(4 * ty + 2) * 17 + tx] = pq.z;
    rq[(4 * ty + 3) * 17 + tx] = pq.w;
    __syncthreads();
    if (tid < 64) {
      float S = 0.f, Q = 0.f;
#pragma unroll
      for (int t = 0; t < 16; ++t) { S += rs[tid * 17 + t]; Q += rq[tid * 17 + t]; }
      int slot = blockIdx.x & 7;
      atomicAdd(&nextsums[slot * 128 + tid], S);
      atomicAdd(&nextsums[slot * 128 + 64 + tid], Q);
    }
  }
}

extern "C" void kernel_launch(void* const* d_in, const int* in_sizes, int n_in,
                              void* d_out, int out_size, void* d_ws, size_t ws_size,
                              hipStream_t stream) {
  const float* x = (const float*)d_in[0];
  const int* edge_index = (const int*)d_in[1];
  const float* edge_attr = (const float*)d_in[2];
  const float* node_W = (const float*)d_in[3];
  const float* node_b = (const float*)d_in[4];
  const float* edge_W = (const float*)d_in[5];
  const float* edge_b = (const float*)d_in[6];
  const float* bn_g = (const float*)d_in[7];
  const float* bn_b = (const float*)d_in[8];
  const float* t = (const float*)d_in[9];
  const float* W1 = (const float*)d_in[10];
  const float* b1 = (const float*)d_in[11];
  const float* ln_g = (const float*)d_in[12];
  const float* ln_b = (const float*)d_in[13];
  const float* W2 = (const float*)d_in[14];
  const float* b2 = (const float*)d_in[15];

  int N = in_sizes[0] / HDIM;
  int E = in_sizes[1] / 2;
  const int* srcp = edge_index;
  const int* dstp = edge_index + E;

  char* ws = (char*)d_ws;
  size_t off = 0;
  auto alloc = [&](size_t bytes) {
    char* p = ws + off;
    off = (off + bytes + 255) & ~(size_t)255;
    return p;
  };
  int* deg = (int*)alloc((size_t)N * 4);
  int* rowstart = (int*)alloc(((size_t)N + 1) * 4);
  int* idxw = (int*)alloc((size_t)E * 4);
  int* partials = (int*)alloc(1024 * 4);
  float* bnsums = (float*)alloc(3 * 1024 * 4);  // 3 layers x 8 slots x 128
  char* recs = (char*)alloc((size_t)E * 32);
  float* h = (float*)alloc((size_t)N * 64 * 4);
  float* outv = (float*)alloc((size_t)N * 64 * 4);
  unsigned short* hn = (unsigned short*)alloc((size_t)N * 64 * 2);
  (void)ws_size; (void)n_in; (void)out_size;

  int nb = (N + 255) / 256;
  hipMemsetAsync(bnsums, 0, 3 * 1024 * 4, stream);
  init_h_stats_kernel<<<512, 256, 0, stream>>>(x, node_W, node_b, h, bnsums, deg, N);
  deg_kernel<<<(E + 255) / 256, 256, 0, stream>>>(dstp, deg, idxw, E);
  scan_part_kernel<<<nb, 256, 0, stream>>>(deg, partials, N);
  scan_top_kernel<<<1, 1024, 0, stream>>>(partials, nb);
  scan_fill_kernel<<<nb, 256, 0, stream>>>(deg, partials, rowstart, N, E);
  fill_kernel<<<(E + 255) / 256, 256, 0, stream>>>(srcp, dstp, idxw, rowstart, edge_attr, recs, E);

  float invN = 1.0f / (float)N;
  int mlp_blocks = (N + 63) / 64;
  for (int l = 0; l < 3; ++l) {
    bn_apply_kernel<<<512, 256, 0, stream>>>(h, bnsums + l * 1024, bn_g + l * 64,
                                             bn_b + l * 64, hn, N, invN);
    aggregate_kernel<<<(N + 3) / 4, 256, 0, stream>>>(hn, rowstart, recs, edge_W, edge_b,
                                                      t + l, outv, N);
    float* hout = (l == 2) ? (float*)d_out : h;
    float* nxt = (l == 2) ? nullptr : (bnsums + (l + 1) * 1024);
    mlp_tile_kernel<<<mlp_blocks, 256, 0, stream>>>(outv, h, W1 + (size_t)l * 8192, b1 + l * 128,
                                                    ln_g + l * 128, ln_b + l * 128,
                                                    W2 + (size_t)l * 8192, b2 + l * 64, hout, nxt, N);
  }
}

// Round 13
// 266.518 us; speedup vs baseline: 1.1972x; 1.1972x over previous
//
#include <hip/hip_runtime.h>
#include <hip/hip_bf16.h>
#include <hip/hip_fp16.h>

constexpr int HDIM = 8;
constexpr int EDIM = 8;

typedef _Float16 half8 __attribute__((ext_vector_type(8)));
typedef float f32x4 __attribute__((ext_vector_type(4)));
union H8U { uint4 u; half8 h; };

__device__ __forceinline__ unsigned pack2h(float a, float b) {
  __half2 h = __floats2half2_rn(a, b);
  union { __half2 h2; unsigned u; } u;
  u.h2 = h;
  return u.u;
}

__device__ __forceinline__ __half2 u2h2(unsigned v) {
  union { unsigned u; __half2 h2; } u;
  u.u = v;
  return u.h2;
}

// h = x @ node_W + node_b, fused with layer-0 BN stats (8-slot) and deg zeroing.
__global__ __launch_bounds__(256) void init_h_stats_kernel(
    const float* __restrict__ x, const float* __restrict__ W, const float* __restrict__ b,
    float* __restrict__ h, float* __restrict__ sums, int* __restrict__ deg, int n) {
  __shared__ float reds[256], redq[256];
  int tid = threadIdx.x, lane = tid & 63;
  int gtid = blockIdx.x * 256 + tid;
  for (int i = gtid; i < n; i += 512 * 256) deg[i] = 0;
  float wc[HDIM];
#pragma unroll
  for (int k = 0; k < HDIM; ++k) wc[k] = W[k * 64 + lane];
  float bc = b[lane];
  float s = 0.f, q = 0.f;
  int total = n * 64;
  for (int gid = gtid; gid < total; gid += 512 * 256) {
    int row = gid >> 6;
    const float* xr = x + (size_t)row * HDIM;
    float acc = bc;
#pragma unroll
    for (int k = 0; k < HDIM; ++k) acc = fmaf(xr[k], wc[k], acc);
    h[gid] = acc;
    s += acc;
    q = fmaf(acc, acc, q);
  }
  reds[tid] = s; redq[tid] = q;
  __syncthreads();
  if (tid < 64) {
    float S = reds[tid] + reds[64 + tid] + reds[128 + tid] + reds[192 + tid];
    float Q = redq[tid] + redq[64 + tid] + redq[128 + tid] + redq[192 + tid];
    int slot = blockIdx.x & 7;
    atomicAdd(&sums[slot * 128 + tid], S);
    atomicAdd(&sums[slot * 128 + 64 + tid], Q);
  }
}

__global__ void deg_kernel(const int* __restrict__ dst, int* __restrict__ deg,
                           int* __restrict__ idxw, int E) {
  int e = blockIdx.x * 256 + threadIdx.x;
  if (e < E) idxw[e] = atomicAdd(&deg[dst[e]], 1);
}

__global__ __launch_bounds__(256) void scan_part_kernel(const int* __restrict__ deg,
                                                        int* __restrict__ partials, int n) {
  __shared__ int sh[256];
  int tid = threadIdx.x, idx = blockIdx.x * 256 + tid;
  int v = (idx < n) ? deg[idx] : 0;
  sh[tid] = v;
  __syncthreads();
  for (int o = 128; o > 0; o >>= 1) {
    if (tid < o) sh[tid] += sh[tid + o];
    __syncthreads();
  }
  if (tid == 0) partials[blockIdx.x] = sh[0];
}

__global__ __launch_bounds__(1024) void scan_top_kernel(int* __restrict__ partials, int nb) {
  __shared__ int sh[1024];
  int tid = threadIdx.x;
  int v = (tid < nb) ? partials[tid] : 0;
  sh[tid] = v;
  __syncthreads();
  for (int o = 1; o < 1024; o <<= 1) {
    int a = (tid >= o) ? sh[tid - o] : 0;
    __syncthreads();
    sh[tid] += a;
    __syncthreads();
  }
  if (tid < nb) partials[tid] = sh[tid] - v;  // exclusive
}

__global__ __launch_bounds__(256) void scan_fill_kernel(
    const int* __restrict__ deg, const int* __restrict__ partials,
    int* __restrict__ rowstart, int n, int total) {
  __shared__ int sh[256];
  int tid = threadIdx.x, idx = blockIdx.x * 256 + tid;
  int v = (idx < n) ? deg[idx] : 0;
  sh[tid] = v;
  __syncthreads();
  for (int o = 1; o < 256; o <<= 1) {
    int a = (tid >= o) ? sh[tid - o] : 0;
    __syncthreads();
    sh[tid] += a;
    __syncthreads();
  }
  if (idx < n) rowstart[idx] = partials[blockIdx.x] + sh[tid] - v;
  if (blockIdx.x == 0 && tid == 0) rowstart[n] = total;
}

// scatter ONE 32B record per edge: {f16 ea[8] (16B), src (4B), pad}. No atomics.
__global__ void fill_kernel(const int* __restrict__ src, const int* __restrict__ dst,
                            const int* __restrict__ idxw, const int* __restrict__ rowstart,
                            const float* __restrict__ edge_attr, char* __restrict__ recs, int E) {
  int e = blockIdx.x * 256 + threadIdx.x;
  if (e >= E) return;
  int d = dst[e];
  int slot = rowstart[d] + idxw[e];
  const float4* ap = (const float4*)(edge_attr + (size_t)e * EDIM);
  float4 a = ap[0], c = ap[1];
  uint4 rv;
  rv.x = pack2h(a.x, a.y);
  rv.y = pack2h(a.z, a.w);
  rv.z = pack2h(c.x, c.y);
  rv.w = pack2h(c.z, c.w);
  char* rb = recs + (size_t)slot * 32;
  *(uint4*)rb = rv;
  *(int*)(rb + 16) = src[e];
}

// Per-layer BN+ReLU applied once per node -> f16 hn buffer
__global__ __launch_bounds__(256) void bn_apply_kernel(
    const float* __restrict__ h, const float* __restrict__ sums,
    const float* __restrict__ bn_g, const float* __restrict__ bn_b,
    unsigned short* __restrict__ hn, int n, float invN) {
  int tid0 = blockIdx.x * 256 + threadIdx.x;
  int lane = tid0 & 63;
  float ssum = 0.f, qsum = 0.f;
#pragma unroll
  for (int k = 0; k < 8; ++k) {
    ssum += sums[k * 128 + lane];
    qsum += sums[k * 128 + 64 + lane];
  }
  float mu = ssum * invN;
  float var = qsum * invN - mu * mu;
  float a = rsqrtf(var + 1e-5f) * bn_g[lane];
  float c = bn_b[lane] - mu * a;
  int total = n * 64;
  for (int gid = tid0; gid < total; gid += 512 * 256) {
    float v = fmaxf(fmaf(h[gid], a, c), 0.f);
    hn[gid] = __half_as_ushort(__float2half(v));
  }
}

// Fused message + softmax-agg on precomputed f16 hn. 1 wave/node, lane=channel.
__global__ __launch_bounds__(256) void aggregate_kernel(
    const unsigned short* __restrict__ hn, const int* __restrict__ rowstart,
    const char* __restrict__ recs, const float* __restrict__ edge_W,
    const float* __restrict__ edge_b, const float* __restrict__ t,
    float* __restrict__ out, int n) {
  int lane = threadIdx.x & 63;
  int node = blockIdx.x * 4 + (threadIdx.x >> 6);
  if (node >= n) return;
  __half2 wc2[4];
#pragma unroll
  for (int k = 0; k < 4; ++k)
    wc2[k] = __floats2half2_rn(edge_W[(2 * k) * 64 + lane], edge_W[(2 * k + 1) * 64 + lane]);
  float eb = edge_b[lane];
  float tt = t[0];
  int s0 = __builtin_amdgcn_readfirstlane(rowstart[node]);
  int s1 = __builtin_amdgcn_readfirstlane(rowstart[node + 1]);
  float hd = __half2float(__ushort_as_half(hn[(size_t)node * 64 + lane]));
  float den = 0.f, num = 0.f;
#define EDGE_STEP(HU, RV)                                                      \
  {                                                                            \
    __half2 acc = __hmul2(u2h2(RV.w), wc2[3]);                                 \
    acc = __hfma2(u2h2(RV.z), wc2[2], acc);                                    \
    acc = __hfma2(u2h2(RV.y), wc2[1], acc);                                    \
    acc = __hfma2(u2h2(RV.x), wc2[0], acc);                                    \
    float ev = __low2float(acc) + __high2float(acc) + eb;                      \
    float hnv = __half2float(__ushort_as_half(HU));                            \
    float msg = fmaxf(hnv + ev, 0.f) + 1e-7f;                                  \
    float p = __expf(msg * tt);                                                \
    den += p;                                                                  \
    num = fmaf(p, msg, num);                                                   \
  }
  int j = s0;
  for (; j + 8 <= s1; j += 8) {
    const char* rb = recs + (size_t)j * 32;
    uint4 r0 = *(const uint4*)(rb);
    uint4 r1 = *(const uint4*)(rb + 32);
    uint4 r2 = *(const uint4*)(rb + 64);
    uint4 r3 = *(const uint4*)(rb + 96);
    uint4 r4 = *(const uint4*)(rb + 128);
    uint4 r5 = *(const uint4*)(rb + 160);
    uint4 r6 = *(const uint4*)(rb + 192);
    uint4 r7 = *(const uint4*)(rb + 224);
    int i0 = *(const int*)(rb + 16);
    int i1 = *(const int*)(rb + 48);
    int i2 = *(const int*)(rb + 80);
    int i3 = *(const int*)(rb + 112);
    int i4 = *(const int*)(rb + 144);
    int i5 = *(const int*)(rb + 176);
    int i6 = *(const int*)(rb + 208);
    int i7 = *(const int*)(rb + 240);
    unsigned short u0 = hn[(size_t)i0 * 64 + lane];
    unsigned short u1 = hn[(size_t)i1 * 64 + lane];
    unsigned short u2 = hn[(size_t)i2 * 64 + lane];
    unsigned short u3 = hn[(size_t)i3 * 64 + lane];
    unsigned short u4 = hn[(size_t)i4 * 64 + lane];
    unsigned short u5 = hn[(size_t)i5 * 64 + lane];
    unsigned short u6 = hn[(size_t)i6 * 64 + lane];
    unsigned short u7 = hn[(size_t)i7 * 64 + lane];
    EDGE_STEP(u0, r0)
    EDGE_STEP(u1, r1)
    EDGE_STEP(u2, r2)
    EDGE_STEP(u3, r3)
    EDGE_STEP(u4, r4)
    EDGE_STEP(u5, r5)
    EDGE_STEP(u6, r6)
    EDGE_STEP(u7, r7)
  }
  for (; j + 4 <= s1; j += 4) {
    const char* rb = recs + (size_t)j * 32;
    uint4 r0 = *(const uint4*)(rb);
    uint4 r1 = *(const uint4*)(rb + 32);
    uint4 r2 = *(const uint4*)(rb + 64);
    uint4 r3 = *(const uint4*)(rb + 96);
    int i0 = *(const int*)(rb + 16);
    int i1 = *(const int*)(rb + 48);
    int i2 = *(const int*)(rb + 80);
    int i3 = *(const int*)(rb + 112);
    unsigned short u0 = hn[(size_t)i0 * 64 + lane];
    unsigned short u1 = hn[(size_t)i1 * 64 + lane];
    unsigned short u2 = hn[(size_t)i2 * 64 + lane];
    unsigned short u3 = hn[(size_t)i3 * 64 + lane];
    EDGE_STEP(u0, r0)
    EDGE_STEP(u1, r1)
    EDGE_STEP(u2, r2)
    EDGE_STEP(u3, r3)
  }
  for (; j < s1; ++j) {
    const char* rb = recs + (size_t)j * 32;
    uint4 r0 = *(const uint4*)(rb);
    int i0 = *(const int*)(rb + 16);
    unsigned short u0 = hn[(size_t)i0 * 64 + lane];
    EDGE_STEP(u0, r0)
  }
#undef EDGE_STEP
  out[(size_t)node * 64 + lane] = num / fmaxf(den, 1e-16f) + hd;
}

// MFMA MLP: 64 nodes/block, 4 waves = 4 M-tiles. All operands staged in LDS in
// fragment order (1 ds_read_b128/frag). GEMM1: 16 mfma/wave; in-register LN on
// C-frags (col=lane&15, row=(lane>>4)*4+reg); z written f16 into GEMM2 A-frag
// layout (own-wave region); GEMM2: 16 mfma/wave. LDS 40KB -> 4 blocks/CU.
__global__ __launch_bounds__(256) void mlp_mfma_kernel(
    const float* __restrict__ outv, const float* __restrict__ h_in,
    const float* __restrict__ W1, const float* __restrict__ b1,
    const float* __restrict__ lng, const float* __restrict__ lnb,
    const float* __restrict__ W2, const float* __restrict__ b2,
    float* __restrict__ h_out, float* __restrict__ nextsums, int n) {
  __shared__ uint4 lds[2560];  // 40KB: [0,512)=xa, [512,1536)=wb1|wb2, [1536,2560)=zf
  const int tid = threadIdx.x;
  const int wv = tid >> 6, l = tid & 63;
  const int n0 = blockIdx.x * 64;
  uint4* XA = lds;
  uint4* WB = lds + 512;   // wb1 then wb2
  uint4* ZF = lds + 1536;
  // ---- stage xa: x (outv) -> f16 A-frags. chunk c: node=c>>3, k8=c&7 ----
#pragma unroll
  for (int i = 0; i < 2; ++i) {
    int c = tid + i * 256;
    int node = c >> 3, k8 = c & 7;
    int nd = n0 + node;
    half8 hv;
    if (nd < n) {
      const float* xp = outv + (size_t)nd * 64 + k8 * 8;
#pragma unroll
      for (int j = 0; j < 8; ++j) hv[j] = (_Float16)xp[j];
    } else {
#pragma unroll
      for (int j = 0; j < 8; ++j) hv[j] = (_Float16)0.f;
    }
    H8U u; u.h = hv;
    int mt = node >> 4, kt = k8 >> 2;
    int lanep = ((k8 & 3) << 4) | (node & 15);
    XA[(mt * 2 + kt) * 64 + lanep] = u.u;
  }
  // ---- stage wb1: W1[64k][128n] -> f16 B-frags (nt 0..7, kt 0..1) ----
#pragma unroll
  for (int i = 0; i < 4; ++i) {
    int c = tid + i * 256;
    int fid = c >> 6, lp = c & 63;
    int nt = fid >> 1, kt = fid & 1;
    int ncol = (nt << 4) | (lp & 15);
    int k0 = kt * 32 + (lp >> 4) * 8;
    half8 hv;
#pragma unroll
    for (int j = 0; j < 8; ++j) hv[j] = (_Float16)W1[(size_t)(k0 + j) * 128 + ncol];
    H8U u; u.h = hv;
    WB[fid * 64 + lp] = u.u;
  }
  __syncthreads();
  // ---- GEMM1: y[16 nodes][128] per wave ----
  f32x4 cfr[8];
#pragma unroll
  for (int nt = 0; nt < 8; ++nt) cfr[nt] = (f32x4){0.f, 0.f, 0.f, 0.f};
  {
    H8U a0, a1;
    a0.u = XA[(wv * 2 + 0) * 64 + l];
    a1.u = XA[(wv * 2 + 1) * 64 + l];
#pragma unroll
    for (int nt = 0; nt < 8; ++nt) {
      H8U b0, b1u;
      b0.u = WB[(nt * 2 + 0) * 64 + l];
      b1u.u = WB[(nt * 2 + 1) * 64 + l];
      cfr[nt] = __builtin_amdgcn_mfma_f32_16x16x32_f16(a0.h, b0.h, cfr[nt], 0, 0, 0);
      cfr[nt] = __builtin_amdgcn_mfma_f32_16x16x32_f16(a1.h, b1u.h, cfr[nt], 0, 0, 0);
    }
  }
  // bias + LN stats in-register
  int col = l & 15;
  float s4[4] = {0.f, 0.f, 0.f, 0.f}, q4[4] = {0.f, 0.f, 0.f, 0.f};
#pragma unroll
  for (int nt = 0; nt < 8; ++nt) {
    float bb = b1[nt * 16 + col];
#pragma unroll
    for (int r = 0; r < 4; ++r) {
      float v = cfr[nt][r] + bb;
      cfr[nt][r] = v;
      s4[r] += v;
      q4[r] = fmaf(v, v, q4[r]);
    }
  }
#pragma unroll
  for (int off = 1; off < 16; off <<= 1) {
#pragma unroll
    for (int r = 0; r < 4; ++r) {
      s4[r] += __shfl_xor(s4[r], off, 64);
      q4[r] += __shfl_xor(q4[r], off, 64);
    }
  }
  float mu4[4], rs4[4];
#pragma unroll
  for (int r = 0; r < 4; ++r) {
    float mu = s4[r] * (1.f / 128.f);
    float var = q4[r] * (1.f / 128.f) - mu * mu;
    mu4[r] = mu;
    rs4[r] = rsqrtf(var + 1e-5f);
  }
  // z = relu(LN(y)) -> f16 into GEMM2 A-frag layout (own-wave region, no barrier)
  {
    unsigned short* ZB = (unsigned short*)ZF;
#pragma unroll
    for (int nt = 0; nt < 8; ++nt) {
      int ch = nt * 16 + col;
      int kt2 = ch >> 5, kl = ch & 31;
      float g = lng[ch], bb = lnb[ch];
#pragma unroll
      for (int r = 0; r < 4; ++r) {
        int row = (l >> 4) * 4 + r;
        float zv = fmaxf((cfr[nt][r] - mu4[r]) * rs4[r] * g + bb, 0.f);
        int lanep = ((kl >> 3) << 4) | row;
        ZB[((wv * 4 + kt2) * 64 + lanep) * 8 + (kl & 7)] = __half_as_ushort(__float2half(zv));
      }
    }
  }
  __syncthreads();  // all waves done reading wb1/xa; WB becomes wb2
  // ---- stage wb2: W2[128k][64n] -> f16 B-frags (nt2 0..3, kt2 0..3) ----
#pragma unroll
  for (int i = 0; i < 4; ++i) {
    int c = tid + i * 256;
    int fid = c >> 6, lp = c & 63;
    int nt2 = fid >> 2, kt2 = fid & 3;
    int ncol = (nt2 << 4) | (lp & 15);
    int k0 = kt2 * 32 + (lp >> 4) * 8;
    half8 hv;
#pragma unroll
    for (int j = 0; j < 8; ++j) hv[j] = (_Float16)W2[(size_t)(k0 + j) * 64 + ncol];
    H8U u; u.h = hv;
    WB[fid * 64 + lp] = u.u;
  }
  __syncthreads();
  // ---- GEMM2: out[16 nodes][64] per wave ----
  f32x4 dfr[4];
#pragma unroll
  for (int nt2 = 0; nt2 < 4; ++nt2) dfr[nt2] = (f32x4){0.f, 0.f, 0.f, 0.f};
  {
    H8U za[4];
#pragma unroll
    for (int kt2 = 0; kt2 < 4; ++kt2) za[kt2].u = ZF[(wv * 4 + kt2) * 64 + l];
#pragma unroll
    for (int nt2 = 0; nt2 < 4; ++nt2) {
#pragma unroll
      for (int kt2 = 0; kt2 < 4; ++kt2) {
        H8U bu;
        bu.u = WB[(nt2 * 4 + kt2) * 64 + l];
        dfr[nt2] = __builtin_amdgcn_mfma_f32_16x16x32_f16(za[kt2].h, bu.h, dfr[nt2], 0, 0, 0);
      }
    }
  }
  // epilogue: residual + store + per-channel stats
  float ssum[4] = {0.f, 0.f, 0.f, 0.f}, qsum[4] = {0.f, 0.f, 0.f, 0.f};
#pragma unroll
  for (int nt2 = 0; nt2 < 4; ++nt2) {
    int ch2 = nt2 * 16 + col;
    float bb = b2[ch2];
#pragma unroll
    for (int r = 0; r < 4; ++r) {
      int nd = n0 + wv * 16 + (l >> 4) * 4 + r;
      if (nd < n) {
        float v = h_in[(size_t)nd * 64 + ch2] + dfr[nt2][r] + bb;
        h_out[(size_t)nd * 64 + ch2] = v;
        ssum[nt2] += v;
        qsum[nt2] = fmaf(v, v, qsum[nt2]);
      }
    }
  }
  if (nextsums != nullptr) {
    // reduce across the 4 row-groups (lanes l, l^16, l^32, l^48 share a column)
#pragma unroll
    for (int nt2 = 0; nt2 < 4; ++nt2) {
      ssum[nt2] += __shfl_xor(ssum[nt2], 16, 64);
      ssum[nt2] += __shfl_xor(ssum[nt2], 32, 64);
      qsum[nt2] += __shfl_xor(qsum[nt2], 16, 64);
      qsum[nt2] += __shfl_xor(qsum[nt2], 32, 64);
    }
    // per-wave partials -> LDS (own zf region is dead now), then one pass of 64
    float* SS = (float*)(ZF + wv * 256);  // 64 s + 64 q floats per wave
    if (l < 16) {
#pragma unroll
      for (int nt2 = 0; nt2 < 4; ++nt2) {
        SS[nt2 * 16 + l] = ssum[nt2];
        SS[64 + nt2 * 16 + l] = qsum[nt2];
      }
    }
    __syncthreads();
    if (tid < 64) {
      float S = 0.f, Q = 0.f;
#pragma unroll
      for (int w = 0; w < 4; ++w) {
        const float* P = (const float*)(ZF + w * 256);
        S += P[tid];
        Q += P[64 + tid];
      }
      int slot = blockIdx.x & 7;
      atomicAdd(&nextsums[slot * 128 + tid], S);
      atomicAdd(&nextsums[slot * 128 + 64 + tid], Q);
    }
  }
}

extern "C" void kernel_launch(void* const* d_in, const int* in_sizes, int n_in,
                              void* d_out, int out_size, void* d_ws, size_t ws_size,
                              hipStream_t stream) {
  const float* x = (const float*)d_in[0];
  const int* edge_index = (const int*)d_in[1];
  const float* edge_attr = (const float*)d_in[2];
  const float* node_W = (const float*)d_in[3];
  const float* node_b = (const float*)d_in[4];
  const float* edge_W = (const float*)d_in[5];
  const float* edge_b = (const float*)d_in[6];
  const float* bn_g = (const float*)d_in[7];
  const float* bn_b = (const float*)d_in[8];
  const float* t = (const float*)d_in[9];
  const float* W1 = (const float*)d_in[10];
  const float* b1 = (const float*)d_in[11];
  const float* ln_g = (const float*)d_in[12];
  const float* ln_b = (const float*)d_in[13];
  const float* W2 = (const float*)d_in[14];
  const float* b2 = (const float*)d_in[15];

  int N = in_sizes[0] / HDIM;
  int E = in_sizes[1] / 2;
  const int* srcp = edge_index;
  const int* dstp = edge_index + E;

  char* ws = (char*)d_ws;
  size_t off = 0;
  auto alloc = [&](size_t bytes) {
    char* p = ws + off;
    off = (off + bytes + 255) & ~(size_t)255;
    return p;
  };
  int* deg = (int*)alloc((size_t)N * 4);
  int* rowstart = (int*)alloc(((size_t)N + 1) * 4);
  int* idxw = (int*)alloc((size_t)E * 4);
  int* partials = (int*)alloc(1024 * 4);
  float* bnsums = (float*)alloc(3 * 1024 * 4);  // 3 layers x 8 slots x 128
  char* recs = (char*)alloc((size_t)E * 32);
  float* h = (float*)alloc((size_t)N * 64 * 4);
  float* outv = (float*)alloc((size_t)N * 64 * 4);
  unsigned short* hn = (unsigned short*)alloc((size_t)N * 64 * 2);
  (void)ws_size; (void)n_in; (void)out_size;

  int nb = (N + 255) / 256;
  hipMemsetAsync(bnsums, 0, 3 * 1024 * 4, stream);
  init_h_stats_kernel<<<512, 256, 0, stream>>>(x, node_W, node_b, h, bnsums, deg, N);
  deg_kernel<<<(E + 255) / 256, 256, 0, stream>>>(dstp, deg, idxw, E);
  scan_part_kernel<<<nb, 256, 0, stream>>>(deg, partials, N);
  scan_top_kernel<<<1, 1024, 0, stream>>>(partials, nb);
  scan_fill_kernel<<<nb, 256, 0, stream>>>(deg, partials, rowstart, N, E);
  fill_kernel<<<(E + 255) / 256, 256, 0, stream>>>(srcp, dstp, idxw, rowstart, edge_attr, recs, E);

  float invN = 1.0f / (float)N;
  int mlp_blocks = (N + 63) / 64;
  for (int l = 0; l < 3; ++l) {
    bn_apply_kernel<<<512, 256, 0, stream>>>(h, bnsums + l * 1024, bn_g + l * 64,
                                             bn_b + l * 64, hn, N, invN);
    aggregate_kernel<<<(N + 3) / 4, 256, 0, stream>>>(hn, rowstart, recs, edge_W, edge_b,
                                                      t + l, outv, N);
    float* hout = (l == 2) ? (float*)d_out : h;
    float* nxt = (l == 2) ? nullptr : (bnsums + (l + 1) * 1024);
    mlp_mfma_kernel<<<mlp_blocks, 256, 0, stream>>>(outv, h, W1 + (size_t)l * 8192, b1 + l * 128,
                                                    ln_g + l * 128, ln_b + l * 128,
                                                    W2 + (size_t)l * 8192, b2 + l * 64, hout, nxt, N);
  }
}

// Round 14
// 254.793 us; speedup vs baseline: 1.2523x; 1.0460x over previous
//
#include <hip/hip_runtime.h>
#include <hip/hip_bf16.h>
#include <hip/hip_fp16.h>

constexpr int HDIM = 8;
constexpr int EDIM = 8;

typedef _Float16 half8 __attribute__((ext_vector_type(8)));
typedef float f32x4 __attribute__((ext_vector_type(4)));
union H8U { uint4 u; half8 h; };

__device__ __forceinline__ unsigned pack2h(float a, float b) {
  __half2 h = __floats2half2_rn(a, b);
  union { __half2 h2; unsigned u; } u;
  u.h2 = h;
  return u.u;
}

__device__ __forceinline__ __half2 u2h2(unsigned v) {
  union { unsigned u; __half2 h2; } u;
  u.u = v;
  return u.h2;
}

// h = x @ node_W + node_b -> f16 h, fused with layer-0 BN stats + deg zeroing.
__global__ __launch_bounds__(256) void init_h_stats_kernel(
    const float* __restrict__ x, const float* __restrict__ W, const float* __restrict__ b,
    unsigned short* __restrict__ h, float* __restrict__ sums, int* __restrict__ deg, int n) {
  __shared__ float reds[256], redq[256];
  int tid = threadIdx.x, lane = tid & 63;
  int gtid = blockIdx.x * 256 + tid;
  for (int i = gtid; i < n; i += 512 * 256) deg[i] = 0;
  float wc[HDIM];
#pragma unroll
  for (int k = 0; k < HDIM; ++k) wc[k] = W[k * 64 + lane];
  float bc = b[lane];
  float s = 0.f, q = 0.f;
  int total = n * 64;
  for (int gid = gtid; gid < total; gid += 512 * 256) {
    int row = gid >> 6;
    const float* xr = x + (size_t)row * HDIM;
    float acc = bc;
#pragma unroll
    for (int k = 0; k < HDIM; ++k) acc = fmaf(xr[k], wc[k], acc);
    h[gid] = __half_as_ushort(__float2half(acc));
    s += acc;
    q = fmaf(acc, acc, q);
  }
  reds[tid] = s; redq[tid] = q;
  __syncthreads();
  if (tid < 64) {
    float S = reds[tid] + reds[64 + tid] + reds[128 + tid] + reds[192 + tid];
    float Q = redq[tid] + redq[64 + tid] + redq[128 + tid] + redq[192 + tid];
    int slot = blockIdx.x & 7;
    atomicAdd(&sums[slot * 128 + tid], S);
    atomicAdd(&sums[slot * 128 + 64 + tid], Q);
  }
}

__global__ void deg_kernel(const int* __restrict__ dst, int* __restrict__ deg,
                           int* __restrict__ idxw, int E) {
  int e = blockIdx.x * 256 + threadIdx.x;
  if (e < E) idxw[e] = atomicAdd(&deg[dst[e]], 1);
}

__global__ __launch_bounds__(256) void scan_part_kernel(const int* __restrict__ deg,
                                                        int* __restrict__ partials, int n) {
  __shared__ int sh[256];
  int tid = threadIdx.x, idx = blockIdx.x * 256 + tid;
  int v = (idx < n) ? deg[idx] : 0;
  sh[tid] = v;
  __syncthreads();
  for (int o = 128; o > 0; o >>= 1) {
    if (tid < o) sh[tid] += sh[tid + o];
    __syncthreads();
  }
  if (tid == 0) partials[blockIdx.x] = sh[0];
}

__global__ __launch_bounds__(1024) void scan_top_kernel(int* __restrict__ partials, int nb) {
  __shared__ int sh[1024];
  int tid = threadIdx.x;
  int v = (tid < nb) ? partials[tid] : 0;
  sh[tid] = v;
  __syncthreads();
  for (int o = 1; o < 1024; o <<= 1) {
    int a = (tid >= o) ? sh[tid - o] : 0;
    __syncthreads();
    sh[tid] += a;
    __syncthreads();
  }
  if (tid < nb) partials[tid] = sh[tid] - v;  // exclusive
}

__global__ __launch_bounds__(256) void scan_fill_kernel(
    const int* __restrict__ deg, const int* __restrict__ partials,
    int* __restrict__ rowstart, int n, int total) {
  __shared__ int sh[256];
  int tid = threadIdx.x, idx = blockIdx.x * 256 + tid;
  int v = (idx < n) ? deg[idx] : 0;
  sh[tid] = v;
  __syncthreads();
  for (int o = 1; o < 256; o <<= 1) {
    int a = (tid >= o) ? sh[tid - o] : 0;
    __syncthreads();
    sh[tid] += a;
    __syncthreads();
  }
  if (idx < n) rowstart[idx] = partials[blockIdx.x] + sh[tid] - v;
  if (blockIdx.x == 0 && tid == 0) rowstart[n] = total;
}

// scatter ONE 32B record per edge: {f16 ea[8] (16B), src (4B), pad}. No atomics.
__global__ void fill_kernel(const int* __restrict__ src, const int* __restrict__ dst,
                            const int* __restrict__ idxw, const int* __restrict__ rowstart,
                            const float* __restrict__ edge_attr, char* __restrict__ recs, int E) {
  int e = blockIdx.x * 256 + threadIdx.x;
  if (e >= E) return;
  int d = dst[e];
  int slot = rowstart[d] + idxw[e];
  const float4* ap = (const float4*)(edge_attr + (size_t)e * EDIM);
  float4 a = ap[0], c = ap[1];
  uint4 rv;
  rv.x = pack2h(a.x, a.y);
  rv.y = pack2h(a.z, a.w);
  rv.z = pack2h(c.x, c.y);
  rv.w = pack2h(c.z, c.w);
  char* rb = recs + (size_t)slot * 32;
  *(uint4*)rb = rv;
  *(int*)(rb + 16) = src[e];
}

// Fused BN+ReLU + message + softmax-agg on f16 h. 1 wave/node, lane=channel.
// BN folded to hn(v) = relu(v*aa + cc); outv written f16 (A-frag-ready for mlp).
__global__ __launch_bounds__(256) void aggregate_kernel(
    const unsigned short* __restrict__ h, const float* __restrict__ sums,
    const float* __restrict__ bn_g, const float* __restrict__ bn_b,
    const int* __restrict__ rowstart, const char* __restrict__ recs,
    const float* __restrict__ edge_W, const float* __restrict__ edge_b,
    const float* __restrict__ t, unsigned short* __restrict__ out, int n, float invN) {
  int lane = threadIdx.x & 63;
  int node = blockIdx.x * 4 + (threadIdx.x >> 6);
  if (node >= n) return;
  float ssum = 0.f, qsum = 0.f;
#pragma unroll
  for (int k = 0; k < 8; ++k) {
    ssum += sums[k * 128 + lane];
    qsum += sums[k * 128 + 64 + lane];
  }
  float mu = ssum * invN;
  float var = qsum * invN - mu * mu;
  float aa = rsqrtf(var + 1e-5f) * bn_g[lane];
  float cc = bn_b[lane] - mu * aa;
  __half2 wc2[4];
#pragma unroll
  for (int k = 0; k < 4; ++k)
    wc2[k] = __floats2half2_rn(edge_W[(2 * k) * 64 + lane], edge_W[(2 * k + 1) * 64 + lane]);
  float eb = edge_b[lane];
  float tt = t[0];
  int s0 = __builtin_amdgcn_readfirstlane(rowstart[node]);
  int s1 = __builtin_amdgcn_readfirstlane(rowstart[node + 1]);
  float hd = fmaxf(fmaf(__half2float(__ushort_as_half(h[(size_t)node * 64 + lane])), aa, cc), 0.f);
  float den = 0.f, num = 0.f;
#define EDGE_STEP(HU, RV)                                                      \
  {                                                                            \
    __half2 acc = __hmul2(u2h2(RV.w), wc2[3]);                                 \
    acc = __hfma2(u2h2(RV.z), wc2[2], acc);                                    \
    acc = __hfma2(u2h2(RV.y), wc2[1], acc);                                    \
    acc = __hfma2(u2h2(RV.x), wc2[0], acc);                                    \
    float ev = __low2float(acc) + __high2float(acc) + eb;                      \
    float hnv = fmaxf(fmaf(__half2float(__ushort_as_half(HU)), aa, cc), 0.f);  \
    float msg = fmaxf(hnv + ev, 0.f) + 1e-7f;                                  \
    float p = __expf(msg * tt);                                                \
    den += p;                                                                  \
    num = fmaf(p, msg, num);                                                   \
  }
  int j = s0;
  for (; j + 8 <= s1; j += 8) {
    const char* rb = recs + (size_t)j * 32;
    uint4 r0 = *(const uint4*)(rb);
    uint4 r1 = *(const uint4*)(rb + 32);
    uint4 r2 = *(const uint4*)(rb + 64);
    uint4 r3 = *(const uint4*)(rb + 96);
    uint4 r4 = *(const uint4*)(rb + 128);
    uint4 r5 = *(const uint4*)(rb + 160);
    uint4 r6 = *(const uint4*)(rb + 192);
    uint4 r7 = *(const uint4*)(rb + 224);
    int i0 = *(const int*)(rb + 16);
    int i1 = *(const int*)(rb + 48);
    int i2 = *(const int*)(rb + 80);
    int i3 = *(const int*)(rb + 112);
    int i4 = *(const int*)(rb + 144);
    int i5 = *(const int*)(rb + 176);
    int i6 = *(const int*)(rb + 208);
    int i7 = *(const int*)(rb + 240);
    unsigned short u0 = h[(size_t)i0 * 64 + lane];
    unsigned short u1 = h[(size_t)i1 * 64 + lane];
    unsigned short u2 = h[(size_t)i2 * 64 + lane];
    unsigned short u3 = h[(size_t)i3 * 64 + lane];
    unsigned short u4 = h[(size_t)i4 * 64 + lane];
    unsigned short u5 = h[(size_t)i5 * 64 + lane];
    unsigned short u6 = h[(size_t)i6 * 64 + lane];
    unsigned short u7 = h[(size_t)i7 * 64 + lane];
    EDGE_STEP(u0, r0)
    EDGE_STEP(u1, r1)
    EDGE_STEP(u2, r2)
    EDGE_STEP(u3, r3)
    EDGE_STEP(u4, r4)
    EDGE_STEP(u5, r5)
    EDGE_STEP(u6, r6)
    EDGE_STEP(u7, r7)
  }
  for (; j + 4 <= s1; j += 4) {
    const char* rb = recs + (size_t)j * 32;
    uint4 r0 = *(const uint4*)(rb);
    uint4 r1 = *(const uint4*)(rb + 32);
    uint4 r2 = *(const uint4*)(rb + 64);
    uint4 r3 = *(const uint4*)(rb + 96);
    int i0 = *(const int*)(rb + 16);
    int i1 = *(const int*)(rb + 48);
    int i2 = *(const int*)(rb + 80);
    int i3 = *(const int*)(rb + 112);
    unsigned short u0 = h[(size_t)i0 * 64 + lane];
    unsigned short u1 = h[(size_t)i1 * 64 + lane];
    unsigned short u2 = h[(size_t)i2 * 64 + lane];
    unsigned short u3 = h[(size_t)i3 * 64 + lane];
    EDGE_STEP(u0, r0)
    EDGE_STEP(u1, r1)
    EDGE_STEP(u2, r2)
    EDGE_STEP(u3, r3)
  }
  for (; j < s1; ++j) {
    const char* rb = recs + (size_t)j * 32;
    uint4 r0 = *(const uint4*)(rb);
    int i0 = *(const int*)(rb + 16);
    unsigned short u0 = h[(size_t)i0 * 64 + lane];
    EDGE_STEP(u0, r0)
  }
#undef EDGE_STEP
  float res = num / fmaxf(den, 1e-16f) + hd;
  out[(size_t)node * 64 + lane] = __half_as_ushort(__float2half(res));
}

// MFMA MLP on f16 streams: A-frag staging is a raw uint4 copy from f16 outv.
// GEMM1 16 mfma/wave; in-register LN; z -> f16 A-frags; GEMM2 16 mfma/wave.
// h residual in/out f16 (layer<2) or f32 d_out (layer 2). LDS 40KB.
__global__ __launch_bounds__(256) void mlp_mfma_kernel(
    const unsigned short* __restrict__ outv, const unsigned short* __restrict__ h_in,
    const float* __restrict__ W1, const float* __restrict__ b1,
    const float* __restrict__ lng, const float* __restrict__ lnb,
    const float* __restrict__ W2, const float* __restrict__ b2,
    unsigned short* __restrict__ hout16, float* __restrict__ hout32,
    float* __restrict__ nextsums, int n) {
  __shared__ uint4 lds[2560];  // 40KB: [0,512)=xa, [512,1536)=wb1|wb2, [1536,2560)=zf
  const int tid = threadIdx.x;
  const int wv = tid >> 6, l = tid & 63;
  const int n0 = blockIdx.x * 64;
  uint4* XA = lds;
  uint4* WB = lds + 512;
  uint4* ZF = lds + 1536;
  // ---- stage xa: outv f16 -> A-frags (raw copy; bit layout already matches) ----
#pragma unroll
  for (int i = 0; i < 2; ++i) {
    int c = tid + i * 256;
    int node = c >> 3, k8 = c & 7;
    int nd = n0 + node;
    uint4 u;
    if (nd < n) {
      u = *(const uint4*)(outv + (size_t)nd * 64 + k8 * 8);
    } else {
      u = make_uint4(0, 0, 0, 0);
    }
    int mt = node >> 4, kt = k8 >> 2;
    int lanep = ((k8 & 3) << 4) | (node & 15);
    XA[(mt * 2 + kt) * 64 + lanep] = u;
  }
  // ---- stage wb1: W1[64k][128n] -> f16 B-frags (nt 0..7, kt 0..1) ----
#pragma unroll
  for (int i = 0; i < 4; ++i) {
    int c = tid + i * 256;
    int fid = c >> 6, lp = c & 63;
    int nt = fid >> 1, kt = fid & 1;
    int ncol = (nt << 4) | (lp & 15);
    int k0 = kt * 32 + (lp >> 4) * 8;
    half8 hv;
#pragma unroll
    for (int j = 0; j < 8; ++j) hv[j] = (_Float16)W1[(size_t)(k0 + j) * 128 + ncol];
    H8U u; u.h = hv;
    WB[fid * 64 + lp] = u.u;
  }
  __syncthreads();
  // ---- GEMM1 ----
  f32x4 cfr[8];
#pragma unroll
  for (int nt = 0; nt < 8; ++nt) cfr[nt] = (f32x4){0.f, 0.f, 0.f, 0.f};
  {
    H8U a0, a1;
    a0.u = XA[(wv * 2 + 0) * 64 + l];
    a1.u = XA[(wv * 2 + 1) * 64 + l];
#pragma unroll
    for (int nt = 0; nt < 8; ++nt) {
      H8U b0, b1u;
      b0.u = WB[(nt * 2 + 0) * 64 + l];
      b1u.u = WB[(nt * 2 + 1) * 64 + l];
      cfr[nt] = __builtin_amdgcn_mfma_f32_16x16x32_f16(a0.h, b0.h, cfr[nt], 0, 0, 0);
      cfr[nt] = __builtin_amdgcn_mfma_f32_16x16x32_f16(a1.h, b1u.h, cfr[nt], 0, 0, 0);
    }
  }
  int col = l & 15;
  float s4[4] = {0.f, 0.f, 0.f, 0.f}, q4[4] = {0.f, 0.f, 0.f, 0.f};
#pragma unroll
  for (int nt = 0; nt < 8; ++nt) {
    float bb = b1[nt * 16 + col];
#pragma unroll
    for (int r = 0; r < 4; ++r) {
      float v = cfr[nt][r] + bb;
      cfr[nt][r] = v;
      s4[r] += v;
      q4[r] = fmaf(v, v, q4[r]);
    }
  }
#pragma unroll
  for (int off = 1; off < 16; off <<= 1) {
#pragma unroll
    for (int r = 0; r < 4; ++r) {
      s4[r] += __shfl_xor(s4[r], off, 64);
      q4[r] += __shfl_xor(q4[r], off, 64);
    }
  }
  float mu4[4], rs4[4];
#pragma unroll
  for (int r = 0; r < 4; ++r) {
    float mu = s4[r] * (1.f / 128.f);
    float var = q4[r] * (1.f / 128.f) - mu * mu;
    mu4[r] = mu;
    rs4[r] = rsqrtf(var + 1e-5f);
  }
  {
    unsigned short* ZB = (unsigned short*)ZF;
#pragma unroll
    for (int nt = 0; nt < 8; ++nt) {
      int ch = nt * 16 + col;
      int kt2 = ch >> 5, kl = ch & 31;
      float g = lng[ch], bb = lnb[ch];
#pragma unroll
      for (int r = 0; r < 4; ++r) {
        int row = (l >> 4) * 4 + r;
        float zv = fmaxf((cfr[nt][r] - mu4[r]) * rs4[r] * g + bb, 0.f);
        int lanep = ((kl >> 3) << 4) | row;
        ZB[((wv * 4 + kt2) * 64 + lanep) * 8 + (kl & 7)] = __half_as_ushort(__float2half(zv));
      }
    }
  }
  __syncthreads();
  // ---- stage wb2 ----
#pragma unroll
  for (int i = 0; i < 4; ++i) {
    int c = tid + i * 256;
    int fid = c >> 6, lp = c & 63;
    int nt2 = fid >> 2, kt2 = fid & 3;
    int ncol = (nt2 << 4) | (lp & 15);
    int k0 = kt2 * 32 + (lp >> 4) * 8;
    half8 hv;
#pragma unroll
    for (int j = 0; j < 8; ++j) hv[j] = (_Float16)W2[(size_t)(k0 + j) * 64 + ncol];
    H8U u; u.h = hv;
    WB[fid * 64 + lp] = u.u;
  }
  __syncthreads();
  // ---- GEMM2 ----
  f32x4 dfr[4];
#pragma unroll
  for (int nt2 = 0; nt2 < 4; ++nt2) dfr[nt2] = (f32x4){0.f, 0.f, 0.f, 0.f};
  {
    H8U za[4];
#pragma unroll
    for (int kt2 = 0; kt2 < 4; ++kt2) za[kt2].u = ZF[(wv * 4 + kt2) * 64 + l];
#pragma unroll
    for (int nt2 = 0; nt2 < 4; ++nt2) {
#pragma unroll
      for (int kt2 = 0; kt2 < 4; ++kt2) {
        H8U bu;
        bu.u = WB[(nt2 * 4 + kt2) * 64 + l];
        dfr[nt2] = __builtin_amdgcn_mfma_f32_16x16x32_f16(za[kt2].h, bu.h, dfr[nt2], 0, 0, 0);
      }
    }
  }
  // epilogue: residual (f16 in) + store (f16 h or f32 d_out) + stats
  float ssum[4] = {0.f, 0.f, 0.f, 0.f}, qsum[4] = {0.f, 0.f, 0.f, 0.f};
#pragma unroll
  for (int nt2 = 0; nt2 < 4; ++nt2) {
    int ch2 = nt2 * 16 + col;
    float bb = b2[ch2];
#pragma unroll
    for (int r = 0; r < 4; ++r) {
      int nd = n0 + wv * 16 + (l >> 4) * 4 + r;
      if (nd < n) {
        float hv = __half2float(__ushort_as_half(h_in[(size_t)nd * 64 + ch2]));
        float v = hv + dfr[nt2][r] + bb;
        if (hout32 != nullptr) {
          hout32[(size_t)nd * 64 + ch2] = v;
        } else {
          hout16[(size_t)nd * 64 + ch2] = __half_as_ushort(__float2half(v));
        }
        ssum[nt2] += v;
        qsum[nt2] = fmaf(v, v, qsum[nt2]);
      }
    }
  }
  if (nextsums != nullptr) {
#pragma unroll
    for (int nt2 = 0; nt2 < 4; ++nt2) {
      ssum[nt2] += __shfl_xor(ssum[nt2], 16, 64);
      ssum[nt2] += __shfl_xor(ssum[nt2], 32, 64);
      qsum[nt2] += __shfl_xor(qsum[nt2], 16, 64);
      qsum[nt2] += __shfl_xor(qsum[nt2], 32, 64);
    }
    float* SS = (float*)(ZF + wv * 256);
    if (l < 16) {
#pragma unroll
      for (int nt2 = 0; nt2 < 4; ++nt2) {
        SS[nt2 * 16 + l] = ssum[nt2];
        SS[64 + nt2 * 16 + l] = qsum[nt2];
      }
    }
    __syncthreads();
    if (tid < 64) {
      float S = 0.f, Q = 0.f;
#pragma unroll
      for (int w = 0; w < 4; ++w) {
        const float* P = (const float*)(ZF + w * 256);
        S += P[tid];
        Q += P[64 + tid];
      }
      int slot = blockIdx.x & 7;
      atomicAdd(&nextsums[slot * 128 + tid], S);
      atomicAdd(&nextsums[slot * 128 + 64 + tid], Q);
    }
  }
}

extern "C" void kernel_launch(void* const* d_in, const int* in_sizes, int n_in,
                              void* d_out, int out_size, void* d_ws, size_t ws_size,
                              hipStream_t stream) {
  const float* x = (const float*)d_in[0];
  const int* edge_index = (const int*)d_in[1];
  const float* edge_attr = (const float*)d_in[2];
  const float* node_W = (const float*)d_in[3];
  const float* node_b = (const float*)d_in[4];
  const float* edge_W = (const float*)d_in[5];
  const float* edge_b = (const float*)d_in[6];
  const float* bn_g = (const float*)d_in[7];
  const float* bn_b = (const float*)d_in[8];
  const float* t = (const float*)d_in[9];
  const float* W1 = (const float*)d_in[10];
  const float* b1 = (const float*)d_in[11];
  const float* ln_g = (const float*)d_in[12];
  const float* ln_b = (const float*)d_in[13];
  const float* W2 = (const float*)d_in[14];
  const float* b2 = (const float*)d_in[15];

  int N = in_sizes[0] / HDIM;
  int E = in_sizes[1] / 2;
  const int* srcp = edge_index;
  const int* dstp = edge_index + E;

  char* ws = (char*)d_ws;
  size_t off = 0;
  auto alloc = [&](size_t bytes) {
    char* p = ws + off;
    off = (off + bytes + 255) & ~(size_t)255;
    return p;
  };
  int* deg = (int*)alloc((size_t)N * 4);
  int* rowstart = (int*)alloc(((size_t)N + 1) * 4);
  int* idxw = (int*)alloc((size_t)E * 4);
  int* partials = (int*)alloc(1024 * 4);
  float* bnsums = (float*)alloc(3 * 1024 * 4);
  char* recs = (char*)alloc((size_t)E * 32);
  unsigned short* h = (unsigned short*)alloc((size_t)N * 64 * 2);
  unsigned short* outv = (unsigned short*)alloc((size_t)N * 64 * 2);
  (void)ws_size; (void)n_in; (void)out_size;

  int nb = (N + 255) / 256;
  hipMemsetAsync(bnsums, 0, 3 * 1024 * 4, stream);
  init_h_stats_kernel<<<512, 256, 0, stream>>>(x, node_W, node_b, h, bnsums, deg, N);
  deg_kernel<<<(E + 255) / 256, 256, 0, stream>>>(dstp, deg, idxw, E);
  scan_part_kernel<<<nb, 256, 0, stream>>>(deg, partials, N);
  scan_top_kernel<<<1, 1024, 0, stream>>>(partials, nb);
  scan_fill_kernel<<<nb, 256, 0, stream>>>(deg, partials, rowstart, N, E);
  fill_kernel<<<(E + 255) / 256, 256, 0, stream>>>(srcp, dstp, idxw, rowstart, edge_attr, recs, E);

  float invN = 1.0f / (float)N;
  int mlp_blocks = (N + 63) / 64;
  for (int l = 0; l < 3; ++l) {
    aggregate_kernel<<<(N + 3) / 4, 256, 0, stream>>>(
        h, bnsums + l * 1024, bn_g + l * 64, bn_b + l * 64, rowstart, recs,
        edge_W, edge_b, t + l, outv, N, invN);
    unsigned short* h16 = (l == 2) ? nullptr : h;
    float* h32 = (l == 2) ? (float*)d_out : nullptr;
    float* nxt = (l == 2) ? nullptr : (bnsums + (l + 1) * 1024);
    mlp_mfma_kernel<<<mlp_blocks, 256, 0, stream>>>(outv, h, W1 + (size_t)l * 8192, b1 + l * 128,
                                                    ln_g + l * 128, ln_b + l * 128,
                                                    W2 + (size_t)l * 8192, b2 + l * 64,
                                                    h16, h32, nxt, N);
  }
}